// Round 5
// baseline (80828.815 us; speedup 1.0000x reference)
//
#include <hip/hip_runtime.h>

#define NN 50000
#define FF 16
#define TH 10
#define EE 800000
#define NBLK 500      // 500 blocks * 4 waves = 2000 waves; 50000/2000 = 25 nodes/wave
#define NWAVES 2000

#define TWO_LOG2E 2.8853900817779268f  // 2*log2(e)

typedef __attribute__((ext_vector_type(2))) float v2f;

__device__ __forceinline__ float fexp2(float x) { return __builtin_amdgcn_exp2f(x); }
__device__ __forceinline__ float frcp(float x) { return __builtin_amdgcn_rcpf(x); }
__device__ __forceinline__ float ftanh_pre(float xs) {
  float e = fexp2(xs);
  return 1.0f - 2.0f * frcp(e + 1.0f);
}
__device__ __forceinline__ v2f mk2(float a, float b) { v2f r; r.x = a; r.y = b; return r; }

// ---------------- preprocessing ----------------

__global__ void count_kernel(const int* __restrict__ ei, int* __restrict__ counts) {
  int e = blockIdx.x * 256 + threadIdx.x;
  if (e < EE) atomicAdd(&counts[ei[EE + e]], 1);
}

__global__ void scan_kernel(const int* __restrict__ counts, int* __restrict__ row_ptr) {
  __shared__ int lds[1024];
  const int CH = (NN + 1023) / 1024;  // 49
  int t = threadIdx.x;
  int beg = t * CH, end = beg + CH;
  if (beg > NN) beg = NN;
  if (end > NN) end = NN;
  int s = 0;
  for (int i = beg; i < end; i++) s += counts[i];
  lds[t] = s;
  __syncthreads();
  for (int off = 1; off < 1024; off <<= 1) {
    int v = (t >= off) ? lds[t - off] : 0;
    __syncthreads();
    lds[t] += v;
    __syncthreads();
  }
  int run = lds[t] - s;  // exclusive prefix
  for (int i = beg; i < end; i++) { row_ptr[i] = run; run += counts[i]; }
  if (t == 1023) row_ptr[NN] = lds[1023];
}

__global__ void fill_kernel(const int* __restrict__ ei, const float* __restrict__ ea,
                            const int* __restrict__ row_ptr, int* __restrict__ cursor,
                            int* __restrict__ src_sorted, float* __restrict__ ea_sorted) {
  int e = blockIdx.x * 256 + threadIdx.x;
  if (e >= EE) return;
  int d = ei[EE + e];
  int pos = row_ptr[d] + atomicAdd(&cursor[d], 1);
  src_sorted[pos] = ei[e];
  ((float4*)ea_sorted)[pos] = ((const float4*)ea)[e];
}

__global__ void times_kernel(const float* __restrict__ t, float* __restrict__ dts,
                             float* __restrict__ tis) {
  int u = threadIdx.x;
  if (u >= 40) return;
  int iv = u >> 2, fr = u & 3;
  float dti = (t[iv + 1] - t[iv]) * 0.25f;
  dts[u] = dti;
  float t0 = t[iv] + (float)fr * dti;
  const float C[6] = {0.0f, 0.2f, 0.3f, 0.8f, (float)(8.0 / 9.0), 1.0f};
  for (int s = 0; s < 6; s++) tis[u * 6 + s] = t0 + C[s] * dti;
}

// aug_pre[n][j] = b1n[j] + sum_i aug[n][i] * W1n[32+i][j]   (176-dim aug)
__global__ __launch_bounds__(256) void augpre_kernel(
    const float* __restrict__ xh, const float* __restrict__ xm,
    const float* __restrict__ W1n, const float* __restrict__ b1n,
    float* __restrict__ aug_pre) {
  __shared__ float Wl[176 * 64];
  __shared__ float augl[4][176];
  for (int i = threadIdx.x; i < 176 * 64; i += 256) Wl[i] = W1n[32 * 64 + i];
  __syncthreads();
  int wv = threadIdx.x >> 6, j = threadIdx.x & 63;
  float bj = b1n[j];
  for (int base = blockIdx.x * 4; base < NN; base += gridDim.x * 4) {
    int n = base + wv;  // NN % 4 == 0, always valid
    if (j < 16) {
      int f = j;
      float xv[TH], mv[TH], summ = 0.f;
      #pragma unroll
      for (int tt = 0; tt < TH; tt++) {
        xv[tt] = xh[(tt * NN + n) * FF + f];
        mv[tt] = xm[tt * NN + n];
        summ += mv[tt];
      }
      float cnt = fmaxf(summ, 1.0f);
      float mean = 0.f;
      #pragma unroll
      for (int tt = 0; tt < TH; tt++) mean += xv[tt] * mv[tt];
      mean *= frcp(cnt);
      float var = 0.f;
      #pragma unroll
      for (int tt = 0; tt < TH; tt++) { float d = xv[tt] - mean; var += d * d * mv[tt]; }
      var *= frcp(cnt);
      #pragma unroll
      for (int tt = 0; tt < TH - 1; tt++)
        augl[wv][tt * 16 + f] = (xv[tt + 1] - xv[tt]) * (mv[tt + 1] * mv[tt]);
      augl[wv][144 + f] = mean;
      augl[wv][160 + f] = var;
    }
    __syncthreads();
    float acc = bj;
    #pragma unroll 8
    for (int i = 0; i < 176; i++) acc += augl[wv][i] * Wl[i * 64 + j];
    aug_pre[n * 64 + j] = acc;
    __syncthreads();
  }
}

// ---------------- persistent megakernel (normal launch + software grid barrier) ----------------

struct MA {
  float* xA; float* xB; float* xiA; float* xiB;
  float* k0; float* k1; float* k2; float* k3; float* k4; float* k5;
  const int* row_ptr; const int* srcs;
  const float* eas; const float* aug_pre; const float* dts; const float* tis;
  const float* W1m; const float* b1m; const float* W2m; const float* b2m;
  const float* W1n; const float* W2n; const float* b2n;
  float* out; const int* mask_idx;
  int* bar;
};

#define EDOT2(X0, X1, X2, X3, EA, H)                                  \
  H = __builtin_elementwise_fma(mk2(X0.x, X0.y), Uc2[0], H);          \
  H = __builtin_elementwise_fma(mk2(X0.z, X0.w), Uc2[1], H);          \
  H = __builtin_elementwise_fma(mk2(X1.x, X1.y), Uc2[2], H);          \
  H = __builtin_elementwise_fma(mk2(X1.z, X1.w), Uc2[3], H);          \
  H = __builtin_elementwise_fma(mk2(X2.x, X2.y), Uc2[4], H);          \
  H = __builtin_elementwise_fma(mk2(X2.z, X2.w), Uc2[5], H);          \
  H = __builtin_elementwise_fma(mk2(X3.x, X3.y), Uc2[6], H);          \
  H = __builtin_elementwise_fma(mk2(X3.z, X3.w), Uc2[7], H);          \
  H = __builtin_elementwise_fma(mk2(EA.x, EA.y), Ec2[0], H);          \
  H = __builtin_elementwise_fma(mk2(EA.z, EA.w), Ec2[1], H);

__global__ __launch_bounds__(256, 2) void mega_kernel(MA a) {
  __shared__ float ldsS[4][64];
  __shared__ float ldsA[4][16];
  int wv = threadIdx.x >> 6, j = threadIdx.x & 63;
  int g = j >> 4, kk = j & 15;
  int w = blockIdx.x * 4 + wv;  // 0..1999
  int phase = 0;                 // software grid-barrier phase

  // ---- persistent per-lane weights (loaded ONCE for all 240 stages) ----
  v2f Uc2[8], Ec2[2], Vc2[8], Xc2[8], Ac2[8], W2mT2[8], W2nT2[8];
  #pragma unroll
  for (int i = 0; i < 8; i++) {
    Uc2[i] = mk2(a.W1m[(2 * i) * 64 + j], a.W1m[(2 * i + 1) * 64 + j]) * TWO_LOG2E;
    Vc2[i] = mk2(a.W1m[(16 + 2 * i) * 64 + j], a.W1m[(17 + 2 * i) * 64 + j]) * TWO_LOG2E;
    Xc2[i] = mk2(a.W1n[(2 * i) * 64 + j], a.W1n[(2 * i + 1) * 64 + j]);
    Ac2[i] = mk2(a.W1n[(16 + 2 * i) * 64 + j], a.W1n[(17 + 2 * i) * 64 + j]);
    W2mT2[i] = mk2(a.W2m[(g * 16 + 2 * i) * 16 + kk], a.W2m[(g * 16 + 2 * i + 1) * 16 + kk]);
    W2nT2[i] = mk2(a.W2n[(g * 16 + 2 * i) * 16 + kk], a.W2n[(g * 16 + 2 * i + 1) * 16 + kk]);
  }
  Ec2[0] = mk2(a.W1m[32 * 64 + j], a.W1m[33 * 64 + j]) * TWO_LOG2E;
  Ec2[1] = mk2(a.W1m[34 * 64 + j], a.W1m[35 * 64 + j]) * TWO_LOG2E;
  float b1pre = a.b1m[j] * TWO_LOG2E;
  float tw = a.W1n[208 * 64 + j];
  float b2mk = a.b2m[kk];
  float b2nk = a.b2n[kk];

  float* x = a.xA;
  float* xn = a.xB;

  // software grid barrier: monotonic counter, agent-scope atomics + fences.
  // Release: __threadfence() (L2 writeback) by every thread before arrive.
  // Acquire: spin with acquire load, then __threadfence() (cache invalidate)
  // by every thread after release from the block barrier.
  auto gridbar = [&]() {
    __threadfence();
    __syncthreads();
    if (threadIdx.x == 0) {
      __hip_atomic_fetch_add(a.bar, 1, __ATOMIC_RELEASE, __HIP_MEMORY_SCOPE_AGENT);
      int target = (phase + 1) * NBLK;
      while (__hip_atomic_load(a.bar, __ATOMIC_ACQUIRE, __HIP_MEMORY_SCOPE_AGENT) < target) {
        __builtin_amdgcn_s_sleep(2);
      }
    }
    __syncthreads();
    __threadfence();
    phase++;
  };

  // one vf stage for this wave's 25 nodes + fused RK update
  auto stage = [&](const float* __restrict__ xi, float* __restrict__ xo,
                   float* __restrict__ kself,
                   const float* kp0, const float* kp1, const float* kp2, const float* kp3,
                   float c0, float c1, float c2, float c3, float cown,
                   float dt, float ti, int m) {
    for (int n = w; n < NN; n += NWAVES) {
      // Qj = (b1m + x[dst]·V) prescaled
      const float4* xr = (const float4*)(xi + (size_t)n * 16);
      float4 d0 = xr[0], d1 = xr[1], d2 = xr[2], d3 = xr[3];
      v2f q2 = mk2(b1pre, 0.f);
      q2 = __builtin_elementwise_fma(mk2(d0.x, d0.y), Vc2[0], q2);
      q2 = __builtin_elementwise_fma(mk2(d0.z, d0.w), Vc2[1], q2);
      q2 = __builtin_elementwise_fma(mk2(d1.x, d1.y), Vc2[2], q2);
      q2 = __builtin_elementwise_fma(mk2(d1.z, d1.w), Vc2[3], q2);
      q2 = __builtin_elementwise_fma(mk2(d2.x, d2.y), Vc2[4], q2);
      q2 = __builtin_elementwise_fma(mk2(d2.z, d2.w), Vc2[5], q2);
      q2 = __builtin_elementwise_fma(mk2(d3.x, d3.y), Vc2[6], q2);
      q2 = __builtin_elementwise_fma(mk2(d3.z, d3.w), Vc2[7], q2);
      float Qj = q2.x + q2.y;

      int e0s = __builtin_amdgcn_readfirstlane(a.row_ptr[n]);
      int e1s = __builtin_amdgcn_readfirstlane(a.row_ptr[n + 1]);
      float sj = 0.f;

      for (int e = e0s; e < e1s; e += 64) {
        int cnt = e1s - e;
        if (cnt > 64) cnt = 64;
        int myidx = (j < cnt) ? a.srcs[e + j] : 0;  // 1 coalesced load / <=64 edges
        int p = 0;
        for (; p + 3 < cnt; p += 4) {
          int s0 = __builtin_amdgcn_readlane(myidx, p);
          int s1 = __builtin_amdgcn_readlane(myidx, p + 1);
          int s2 = __builtin_amdgcn_readlane(myidx, p + 2);
          int s3 = __builtin_amdgcn_readlane(myidx, p + 3);
          const float4* r0 = (const float4*)(xi + (size_t)s0 * 16);
          const float4* r1 = (const float4*)(xi + (size_t)s1 * 16);
          const float4* r2 = (const float4*)(xi + (size_t)s2 * 16);
          const float4* r3 = (const float4*)(xi + (size_t)s3 * 16);
          float4 A0 = r0[0], A1 = r0[1], A2 = r0[2], A3 = r0[3];
          float4 B0 = r1[0], B1 = r1[1], B2 = r1[2], B3 = r1[3];
          float4 C0 = r2[0], C1 = r2[1], C2 = r2[2], C3 = r2[3];
          float4 D0 = r3[0], D1 = r3[1], D2 = r3[2], D3 = r3[3];
          float4 ea0 = ((const float4*)a.eas)[e + p];
          float4 ea1 = ((const float4*)a.eas)[e + p + 1];
          float4 ea2 = ((const float4*)a.eas)[e + p + 2];
          float4 ea3 = ((const float4*)a.eas)[e + p + 3];
          v2f h0 = mk2(Qj, 0.f), h1 = h0, h2 = h0, h3 = h0;
          EDOT2(A0, A1, A2, A3, ea0, h0)
          EDOT2(B0, B1, B2, B3, ea1, h1)
          EDOT2(C0, C1, C2, C3, ea2, h2)
          EDOT2(D0, D1, D2, D3, ea3, h3)
          sj += ftanh_pre(h0.x + h0.y) + ftanh_pre(h1.x + h1.y);
          sj += ftanh_pre(h2.x + h2.y) + ftanh_pre(h3.x + h3.y);
        }
        for (; p < cnt; p++) {
          int s0 = __builtin_amdgcn_readlane(myidx, p);
          const float4* r0 = (const float4*)(xi + (size_t)s0 * 16);
          float4 A0 = r0[0], A1 = r0[1], A2 = r0[2], A3 = r0[3];
          float4 ea0 = ((const float4*)a.eas)[e + p];
          v2f h0 = mk2(Qj, 0.f);
          EDOT2(A0, A1, A2, A3, ea0, h0)
          sj += ftanh_pre(h0.x + h0.y);
        }
      }

      // agg[k]: 4-group LDS transpose (wave-local slice, wave-synchronous)
      ldsS[wv][j] = sj;
      v2f pk2 = mk2(0.f, 0.f);
      const v2f* rowS = (const v2f*)&ldsS[wv][g * 16];
      #pragma unroll
      for (int q = 0; q < 8; q++) pk2 = __builtin_elementwise_fma(rowS[q], W2mT2[q], pk2);
      float pk = pk2.x + pk2.y;
      pk += __shfl_xor(pk, 16, 64);
      pk += __shfl_xor(pk, 32, 64);
      ldsA[wv][kk] = pk + (float)(e1s - e0s) * b2mk;

      // node MLP
      v2f g2v = mk2(a.aug_pre[(size_t)n * 64 + j] + ti * tw, 0.f);
      g2v = __builtin_elementwise_fma(mk2(d0.x, d0.y), Xc2[0], g2v);
      g2v = __builtin_elementwise_fma(mk2(d0.z, d0.w), Xc2[1], g2v);
      g2v = __builtin_elementwise_fma(mk2(d1.x, d1.y), Xc2[2], g2v);
      g2v = __builtin_elementwise_fma(mk2(d1.z, d1.w), Xc2[3], g2v);
      g2v = __builtin_elementwise_fma(mk2(d2.x, d2.y), Xc2[4], g2v);
      g2v = __builtin_elementwise_fma(mk2(d2.z, d2.w), Xc2[5], g2v);
      g2v = __builtin_elementwise_fma(mk2(d3.x, d3.y), Xc2[6], g2v);
      g2v = __builtin_elementwise_fma(mk2(d3.z, d3.w), Xc2[7], g2v);
      const v2f* rowA = (const v2f*)&ldsA[wv][0];
      #pragma unroll
      for (int q = 0; q < 8; q++) g2v = __builtin_elementwise_fma(rowA[q], Ac2[q], g2v);
      float h2 = ftanh_pre((g2v.x + g2v.y) * TWO_LOG2E);

      ldsS[wv][j] = h2;
      v2f ok2 = mk2(0.f, 0.f);
      const v2f* rowS2 = (const v2f*)&ldsS[wv][g * 16];
      #pragma unroll
      for (int q = 0; q < 8; q++) ok2 = __builtin_elementwise_fma(rowS2[q], W2nT2[q], ok2);
      float ok = ok2.x + ok2.y;
      ok += __shfl_xor(ok, 16, 64);
      ok += __shfl_xor(ok, 32, 64);

      // epilogue: k write + fused RK combine + optional output scatter
      if (j < 16) {
        float kown = ok + b2nk;
        int base = n * 16 + j;
        kself[base] = kown;
        float v = x[base] + dt * cown * kown;
        if (kp0) v = fmaf(dt * c0, kp0[base], v);
        if (kp1) v = fmaf(dt * c1, kp1[base], v);
        if (kp2) v = fmaf(dt * c2, kp2[base], v);
        if (kp3) v = fmaf(dt * c3, kp3[base], v);
        xo[base] = v;
        if (m >= 0) {
          #pragma unroll
          for (int rr = 0; rr < 10; rr++)
            if (a.mask_idx[rr] == m) a.out[rr * (NN * 16) + base] = v;
        }
      }
    }
    gridbar();
  };

  for (int u = 0; u < 40; ++u) {
    float dt = a.dts[u];
    const float* tb = a.tis + u * 6;
    int m = ((u & 3) == 3) ? (u >> 2) : -1;
    stage(x, a.xiA, a.k0, nullptr, nullptr, nullptr, nullptr,
          0.f, 0.f, 0.f, 0.f, 0.2f, dt, tb[0], -1);
    stage(a.xiA, a.xiB, a.k1, a.k0, nullptr, nullptr, nullptr,
          0.075f, 0.f, 0.f, 0.f, 0.225f, dt, tb[1], -1);
    stage(a.xiB, a.xiA, a.k2, a.k0, a.k1, nullptr, nullptr,
          (float)(44.0 / 45.0), (float)(-56.0 / 15.0), 0.f, 0.f, (float)(32.0 / 9.0),
          dt, tb[2], -1);
    stage(a.xiA, a.xiB, a.k3, a.k0, a.k1, a.k2, nullptr,
          (float)(19372.0 / 6561.0), (float)(-25360.0 / 2187.0), (float)(64448.0 / 6561.0),
          0.f, (float)(-212.0 / 729.0), dt, tb[3], -1);
    stage(a.xiB, a.xiA, a.k4, a.k0, a.k1, a.k2, a.k3,
          (float)(9017.0 / 3168.0), (float)(-355.0 / 33.0), (float)(46732.0 / 5247.0),
          (float)(49.0 / 176.0), (float)(-5103.0 / 18656.0), dt, tb[4], -1);
    stage(a.xiA, xn, a.k5, a.k0, a.k2, a.k3, a.k4,
          (float)(35.0 / 384.0), (float)(500.0 / 1113.0), (float)(125.0 / 192.0),
          (float)(-2187.0 / 6784.0), (float)(11.0 / 84.0), dt, tb[5], m);
    float* tmp = x; x = xn; xn = tmp;
  }
}

// ---------------- host ----------------

extern "C" void kernel_launch(void* const* d_in, const int* in_sizes, int n_in,
                              void* d_out, int out_size, void* d_ws, size_t ws_size,
                              hipStream_t stream) {
  const float* x_hist = (const float*)d_in[0];
  const float* x_mask = (const float*)d_in[1];
  const int* edge_index = (const int*)d_in[2];
  const float* edge_attr = (const float*)d_in[3];
  const float* t = (const float*)d_in[4];
  const int* mask_idx = (const int*)d_in[5];
  const float* W1m = (const float*)d_in[6];
  const float* b1m = (const float*)d_in[7];
  const float* W2m = (const float*)d_in[8];
  const float* b2m = (const float*)d_in[9];
  const float* W1n = (const float*)d_in[10];
  const float* b1n = (const float*)d_in[11];
  const float* W2n = (const float*)d_in[12];
  const float* b2n = (const float*)d_in[13];
  float* out = (float*)d_out;

  size_t off = 0;
  char* wsb = (char*)d_ws;
  auto alloc = [&](size_t bytes) -> void* {
    void* p = (void*)(wsb + off);
    off += (bytes + 255) & ~(size_t)255;
    return p;
  };
  int* row_ptr = (int*)alloc((NN + 1) * sizeof(int));
  int* counts = (int*)alloc(NN * sizeof(int));
  int* src_sorted = (int*)alloc(EE * sizeof(int));
  float* ea_sorted = (float*)alloc((size_t)EE * 4 * sizeof(float));
  float* aug_pre = (float*)alloc((size_t)NN * 64 * sizeof(float));
  float* xA = (float*)alloc((size_t)NN * FF * sizeof(float));
  float* xB = (float*)alloc((size_t)NN * FF * sizeof(float));
  float* xiA = (float*)alloc((size_t)NN * FF * sizeof(float));
  float* xiB = (float*)alloc((size_t)NN * FF * sizeof(float));
  float* kb[6];
  for (int i = 0; i < 6; i++) kb[i] = (float*)alloc((size_t)NN * FF * sizeof(float));
  float* dts = (float*)alloc(40 * sizeof(float));
  float* tis = (float*)alloc(240 * sizeof(float));
  int* bar = (int*)alloc(256);  // grid-barrier counter

  // CSR build + precompute
  hipMemsetAsync(counts, 0, NN * sizeof(int), stream);
  hipMemsetAsync(bar, 0, 256, stream);
  count_kernel<<<(EE + 255) / 256, 256, 0, stream>>>(edge_index, counts);
  scan_kernel<<<1, 1024, 0, stream>>>(counts, row_ptr);
  hipMemsetAsync(counts, 0, NN * sizeof(int), stream);
  fill_kernel<<<(EE + 255) / 256, 256, 0, stream>>>(edge_index, edge_attr, row_ptr, counts,
                                                    src_sorted, ea_sorted);
  augpre_kernel<<<256, 256, 0, stream>>>(x_hist, x_mask, W1n, b1n, aug_pre);
  times_kernel<<<1, 64, 0, stream>>>(t, dts, tis);
  hipMemcpyAsync(xA, x_hist + (size_t)9 * NN * FF, (size_t)NN * FF * sizeof(float),
                 hipMemcpyDeviceToDevice, stream);

  MA margs;
  margs.xA = xA; margs.xB = xB; margs.xiA = xiA; margs.xiB = xiB;
  margs.k0 = kb[0]; margs.k1 = kb[1]; margs.k2 = kb[2];
  margs.k3 = kb[3]; margs.k4 = kb[4]; margs.k5 = kb[5];
  margs.row_ptr = row_ptr; margs.srcs = src_sorted;
  margs.eas = ea_sorted; margs.aug_pre = aug_pre; margs.dts = dts; margs.tis = tis;
  margs.W1m = W1m; margs.b1m = b1m; margs.W2m = W2m; margs.b2m = b2m;
  margs.W1n = W1n; margs.W2n = W2n; margs.b2n = b2n;
  margs.out = out; margs.mask_idx = mask_idx;
  margs.bar = bar;

  mega_kernel<<<NBLK, 256, 0, stream>>>(margs);
}

// Round 6
// 18170.979 us; speedup vs baseline: 4.4482x; 4.4482x over previous
//
#include <hip/hip_runtime.h>

#define NN 50000
#define FF 16
#define TH 10
#define EE 800000

#define TWO_LOG2E 2.8853900817779268f  // 2*log2(e)

typedef __attribute__((ext_vector_type(2))) float v2f;

__device__ __forceinline__ float fexp2(float x) { return __builtin_amdgcn_exp2f(x); }
__device__ __forceinline__ float frcp(float x) { return __builtin_amdgcn_rcpf(x); }
__device__ __forceinline__ float ftanh_pre(float xs) {  // operand pre-scaled by 2log2e
  float e = fexp2(xs);
  return 1.0f - 2.0f * frcp(e + 1.0f);
}
__device__ __forceinline__ v2f mk2(float a, float b) { v2f r; r.x = a; r.y = b; return r; }
__device__ __forceinline__ v2f fma2(v2f a, v2f b, v2f c) { return __builtin_elementwise_fma(a, b, c); }

// ---------------- preprocessing ----------------

__global__ void count_kernel(const int* __restrict__ ei, int* __restrict__ counts) {
  int e = blockIdx.x * 256 + threadIdx.x;
  if (e < EE) atomicAdd(&counts[ei[EE + e]], 1);
}

__global__ void scan_kernel(const int* __restrict__ counts, int* __restrict__ row_ptr) {
  __shared__ int lds[1024];
  const int CH = (NN + 1023) / 1024;  // 49
  int t = threadIdx.x;
  int beg = t * CH, end = beg + CH;
  if (beg > NN) beg = NN;
  if (end > NN) end = NN;
  int s = 0;
  for (int i = beg; i < end; i++) s += counts[i];
  lds[t] = s;
  __syncthreads();
  for (int off = 1; off < 1024; off <<= 1) {
    int v = (t >= off) ? lds[t - off] : 0;
    __syncthreads();
    lds[t] += v;
    __syncthreads();
  }
  int run = lds[t] - s;  // exclusive prefix
  for (int i = beg; i < end; i++) { row_ptr[i] = run; run += counts[i]; }
  if (t == 1023) row_ptr[NN] = lds[1023];
}

__global__ void fill_kernel(const int* __restrict__ ei, const float* __restrict__ ea,
                            const int* __restrict__ row_ptr, int* __restrict__ cursor,
                            int* __restrict__ src_sorted, float* __restrict__ ea_sorted) {
  int e = blockIdx.x * 256 + threadIdx.x;
  if (e >= EE) return;
  int d = ei[EE + e];
  int pos = row_ptr[d] + atomicAdd(&cursor[d], 1);
  src_sorted[pos] = ei[e];
  ((float4*)ea_sorted)[pos] = ((const float4*)ea)[e];
}

__global__ void times_kernel(const float* __restrict__ t, float* __restrict__ dts,
                             float* __restrict__ tis) {
  int u = threadIdx.x;
  if (u >= 40) return;
  int iv = u >> 2, fr = u & 3;
  float dti = (t[iv + 1] - t[iv]) * 0.25f;
  dts[u] = dti;
  float t0 = t[iv] + (float)fr * dti;
  const float C[6] = {0.0f, 0.2f, 0.3f, 0.8f, (float)(8.0 / 9.0), 1.0f};
  for (int s = 0; s < 6; s++) tis[u * 6 + s] = t0 + C[s] * dti;
}

// Prepack per-lane weight blob: 26 chunks, chunk c = 64 lanes x float4 (1 KB),
// lane j's chunk c lives at float4 index c*64 + j  (coalesced across lanes).
//  c0..3  Uc  (W1m rows 0..15,  prescaled by 2log2e)
//  c4..7  Vc  (W1m rows 16..31, prescaled)
//  c8     Ec  (W1m rows 32..35, prescaled)
//  c9     misc: {b1m[j]*2log2e, W1n[208][j] (tw), b2m[j&15], b2n[j&15]}
//  c10..13 Xc (W1n rows 0..15)
//  c14..17 Ac (W1n rows 16..31)
//  c18..21 W2mT (W2m[(g*16+q)][kk])
//  c22..25 W2nT
__global__ void prepack_kernel(const float* __restrict__ W1m, const float* __restrict__ b1m,
                               const float* __restrict__ W2m, const float* __restrict__ b2m,
                               const float* __restrict__ W1n, const float* __restrict__ W2n,
                               const float* __restrict__ b2n, float* __restrict__ wp) {
  int j = threadIdx.x;
  if (j >= 64) return;
  int g = j >> 4, kk = j & 15;
  auto put = [&](int c, int r, float v) { wp[(size_t)(c * 64 + j) * 4 + r] = v; };
  for (int c = 0; c < 4; c++)
    for (int r = 0; r < 4; r++) {
      put(c, r, W1m[(4 * c + r) * 64 + j] * TWO_LOG2E);
      put(4 + c, r, W1m[(16 + 4 * c + r) * 64 + j] * TWO_LOG2E);
      put(10 + c, r, W1n[(4 * c + r) * 64 + j]);
      put(14 + c, r, W1n[(16 + 4 * c + r) * 64 + j]);
      put(18 + c, r, W2m[(g * 16 + 4 * c + r) * 16 + kk]);
      put(22 + c, r, W2n[(g * 16 + 4 * c + r) * 16 + kk]);
    }
  for (int r = 0; r < 4; r++) put(8, r, W1m[(32 + r) * 64 + j] * TWO_LOG2E);
  put(9, 0, b1m[j] * TWO_LOG2E);
  put(9, 1, W1n[208 * 64 + j]);
  put(9, 2, b2m[kk]);
  put(9, 3, b2n[kk]);
}

// aug_pre[n][j] = b1n[j] + sum_i aug[n][i] * W1n[32+i][j]   (176-dim aug)
__global__ __launch_bounds__(256) void augpre_kernel(
    const float* __restrict__ xh, const float* __restrict__ xm,
    const float* __restrict__ W1n, const float* __restrict__ b1n,
    float* __restrict__ aug_pre) {
  __shared__ float Wl[176 * 64];
  __shared__ float augl[4][176];
  for (int i = threadIdx.x; i < 176 * 64; i += 256) Wl[i] = W1n[32 * 64 + i];
  __syncthreads();
  int wv = threadIdx.x >> 6, j = threadIdx.x & 63;
  float bj = b1n[j];
  for (int base = blockIdx.x * 4; base < NN; base += gridDim.x * 4) {
    int n = base + wv;  // NN % 4 == 0
    if (j < 16) {
      int f = j;
      float xv[TH], mv[TH], summ = 0.f;
      #pragma unroll
      for (int tt = 0; tt < TH; tt++) {
        xv[tt] = xh[(tt * NN + n) * FF + f];
        mv[tt] = xm[tt * NN + n];
        summ += mv[tt];
      }
      float cnt = fmaxf(summ, 1.0f);
      float mean = 0.f;
      #pragma unroll
      for (int tt = 0; tt < TH; tt++) mean += xv[tt] * mv[tt];
      mean *= frcp(cnt);
      float var = 0.f;
      #pragma unroll
      for (int tt = 0; tt < TH; tt++) { float d = xv[tt] - mean; var += d * d * mv[tt]; }
      var *= frcp(cnt);
      #pragma unroll
      for (int tt = 0; tt < TH - 1; tt++)
        augl[wv][tt * 16 + f] = (xv[tt + 1] - xv[tt]) * (mv[tt + 1] * mv[tt]);
      augl[wv][144 + f] = mean;
      augl[wv][160 + f] = var;
    }
    __syncthreads();
    float acc = bj;
    #pragma unroll 8
    for (int i = 0; i < 176; i++) acc += augl[wv][i] * Wl[i * 64 + j];
    aug_pre[n * 64 + j] = acc;
    __syncthreads();
  }
}

// ---------------- fused vector field + RK combine ----------------
// 1 node/wave, 50K waves. Weights from prepacked blob: 26 coalesced float4
// loads per wave (edge phase needs only 10). 4-wide edge ILP, pk-fma math.

#define EDOTF(R0, R1, R2, R3, EA, H)                               \
  H = fma2(mk2(R0.x, R0.y), mk2(U0.x, U0.y), H);                   \
  H = fma2(mk2(R0.z, R0.w), mk2(U0.z, U0.w), H);                   \
  H = fma2(mk2(R1.x, R1.y), mk2(U1.x, U1.y), H);                   \
  H = fma2(mk2(R1.z, R1.w), mk2(U1.z, U1.w), H);                   \
  H = fma2(mk2(R2.x, R2.y), mk2(U2.x, U2.y), H);                   \
  H = fma2(mk2(R2.z, R2.w), mk2(U2.z, U2.w), H);                   \
  H = fma2(mk2(R3.x, R3.y), mk2(U3.x, U3.y), H);                   \
  H = fma2(mk2(R3.z, R3.w), mk2(U3.z, U3.w), H);                   \
  H = fma2(mk2(EA.x, EA.y), mk2(E4.x, E4.y), H);                   \
  H = fma2(mk2(EA.z, EA.w), mk2(E4.z, E4.w), H);

__global__ __launch_bounds__(256, 4) void vf_kernel(
    const float* __restrict__ xi, float* __restrict__ kout,
    const float* __restrict__ xb, float* __restrict__ xnext,
    const float* __restrict__ kp0, const float* __restrict__ kp1,
    const float* __restrict__ kp2, const float* __restrict__ kp3,
    float c0, float c1, float c2, float c3, float cown,
    const int* __restrict__ row_ptr, const int* __restrict__ srcs,
    const float* __restrict__ eas, const float* __restrict__ aug_pre,
    const float* __restrict__ dts, const float* __restrict__ tis,
    int u, int tidx, const float* __restrict__ wpack,
    float* __restrict__ dout, const int* __restrict__ mask_idx, int m) {
  __shared__ float ldsS[4][64];
  __shared__ float ldsA[4][16];
  int wv = threadIdx.x >> 6, j = threadIdx.x & 63;
  int g = j >> 4;
  int n = blockIdx.x * 4 + wv;
  int n_s = __builtin_amdgcn_readfirstlane(n);

  const float4* wp = (const float4*)wpack + j;  // lane-j base; chunk c at wp[c*64]

  // edge-phase weights: 10 coalesced float4 loads
  float4 U0 = wp[0 * 64], U1 = wp[1 * 64], U2 = wp[2 * 64], U3 = wp[3 * 64];
  float4 E4 = wp[8 * 64];
  float4 MISC = wp[9 * 64];  // {b1pre, tw, b2mk, b2nk}

  // Qj = b1pre + x[dst]·V (prescaled); V chunks die after this
  float Qj;
  {
    float4 V0 = wp[4 * 64], V1 = wp[5 * 64], V2 = wp[6 * 64], V3 = wp[7 * 64];
    const float4* xr = (const float4*)(xi + (size_t)n_s * 16);
    float4 d0 = xr[0], d1 = xr[1], d2 = xr[2], d3 = xr[3];
    v2f q2 = mk2(MISC.x, 0.f);
    q2 = fma2(mk2(d0.x, d0.y), mk2(V0.x, V0.y), q2);
    q2 = fma2(mk2(d0.z, d0.w), mk2(V0.z, V0.w), q2);
    q2 = fma2(mk2(d1.x, d1.y), mk2(V1.x, V1.y), q2);
    q2 = fma2(mk2(d1.z, d1.w), mk2(V1.z, V1.w), q2);
    q2 = fma2(mk2(d2.x, d2.y), mk2(V2.x, V2.y), q2);
    q2 = fma2(mk2(d2.z, d2.w), mk2(V2.z, V2.w), q2);
    q2 = fma2(mk2(d3.x, d3.y), mk2(V3.x, V3.y), q2);
    q2 = fma2(mk2(d3.z, d3.w), mk2(V3.z, V3.w), q2);
    Qj = q2.x + q2.y;
  }

  int e0s = __builtin_amdgcn_readfirstlane(row_ptr[n_s]);
  int e1s = __builtin_amdgcn_readfirstlane(row_ptr[n_s + 1]);
  float sj = 0.f;

  for (int e = e0s; e < e1s; e += 64) {
    int cnt = e1s - e;
    if (cnt > 64) cnt = 64;
    int myidx = (j < cnt) ? srcs[e + j] : 0;  // 1 coalesced load per <=64 edges
    int p = 0;
    for (; p + 3 < cnt; p += 4) {
      int s0 = __builtin_amdgcn_readlane(myidx, p);
      int s1 = __builtin_amdgcn_readlane(myidx, p + 1);
      int s2 = __builtin_amdgcn_readlane(myidx, p + 2);
      int s3 = __builtin_amdgcn_readlane(myidx, p + 3);
      const float4* r0 = (const float4*)(xi + (size_t)s0 * 16);
      const float4* r1 = (const float4*)(xi + (size_t)s1 * 16);
      const float4* r2 = (const float4*)(xi + (size_t)s2 * 16);
      const float4* r3 = (const float4*)(xi + (size_t)s3 * 16);
      float4 A0 = r0[0], A1 = r0[1], A2 = r0[2], A3 = r0[3];
      float4 B0 = r1[0], B1 = r1[1], B2 = r1[2], B3 = r1[3];
      float4 C0 = r2[0], C1 = r2[1], C2 = r2[2], C3 = r2[3];
      float4 D0 = r3[0], D1 = r3[1], D2 = r3[2], D3 = r3[3];
      float4 ea0 = ((const float4*)eas)[e + p];
      float4 ea1 = ((const float4*)eas)[e + p + 1];
      float4 ea2 = ((const float4*)eas)[e + p + 2];
      float4 ea3 = ((const float4*)eas)[e + p + 3];
      v2f h0 = mk2(Qj, 0.f), h1 = h0, h2 = h0, h3 = h0;
      EDOTF(A0, A1, A2, A3, ea0, h0)
      EDOTF(B0, B1, B2, B3, ea1, h1)
      EDOTF(C0, C1, C2, C3, ea2, h2)
      EDOTF(D0, D1, D2, D3, ea3, h3)
      sj += ftanh_pre(h0.x + h0.y) + ftanh_pre(h1.x + h1.y);
      sj += ftanh_pre(h2.x + h2.y) + ftanh_pre(h3.x + h3.y);
    }
    for (; p < cnt; p++) {
      int s0 = __builtin_amdgcn_readlane(myidx, p);
      const float4* r0 = (const float4*)(xi + (size_t)s0 * 16);
      float4 A0 = r0[0], A1 = r0[1], A2 = r0[2], A3 = r0[3];
      float4 ea0 = ((const float4*)eas)[e + p];
      v2f h0 = mk2(Qj, 0.f);
      EDOTF(A0, A1, A2, A3, ea0, h0)
      sj += ftanh_pre(h0.x + h0.y);
    }
  }

  // agg[k] = sum_j tanh_sum * W2m[j][k] + deg*b2m[k]   (4-group LDS transpose)
  float4 M0 = wp[18 * 64], M1 = wp[19 * 64], M2 = wp[20 * 64], M3 = wp[21 * 64];
  ldsS[wv][j] = sj;
  v2f pk2 = mk2(0.f, 0.f);
  {
    const v2f* rowS = (const v2f*)&ldsS[wv][g * 16];
    pk2 = fma2(rowS[0], mk2(M0.x, M0.y), pk2);
    pk2 = fma2(rowS[1], mk2(M0.z, M0.w), pk2);
    pk2 = fma2(rowS[2], mk2(M1.x, M1.y), pk2);
    pk2 = fma2(rowS[3], mk2(M1.z, M1.w), pk2);
    pk2 = fma2(rowS[4], mk2(M2.x, M2.y), pk2);
    pk2 = fma2(rowS[5], mk2(M2.z, M2.w), pk2);
    pk2 = fma2(rowS[6], mk2(M3.x, M3.y), pk2);
    pk2 = fma2(rowS[7], mk2(M3.z, M3.w), pk2);
  }
  float pk = pk2.x + pk2.y;
  pk += __shfl_xor(pk, 16, 64);
  pk += __shfl_xor(pk, 32, 64);
  ldsA[wv][j & 15] = pk + (float)(e1s - e0s) * MISC.z;

  // node MLP
  float4 X0 = wp[10 * 64], X1 = wp[11 * 64], X2 = wp[12 * 64], X3 = wp[13 * 64];
  float4 AC0 = wp[14 * 64], AC1 = wp[15 * 64], AC2 = wp[16 * 64], AC3 = wp[17 * 64];
  float ti = tis[tidx];
  const float4* xr = (const float4*)(xi + (size_t)n_s * 16);
  float4 d0 = xr[0], d1 = xr[1], d2 = xr[2], d3 = xr[3];
  v2f g2v = mk2(aug_pre[(size_t)n * 64 + j] + ti * MISC.y, 0.f);
  g2v = fma2(mk2(d0.x, d0.y), mk2(X0.x, X0.y), g2v);
  g2v = fma2(mk2(d0.z, d0.w), mk2(X0.z, X0.w), g2v);
  g2v = fma2(mk2(d1.x, d1.y), mk2(X1.x, X1.y), g2v);
  g2v = fma2(mk2(d1.z, d1.w), mk2(X1.z, X1.w), g2v);
  g2v = fma2(mk2(d2.x, d2.y), mk2(X2.x, X2.y), g2v);
  g2v = fma2(mk2(d2.z, d2.w), mk2(X2.z, X2.w), g2v);
  g2v = fma2(mk2(d3.x, d3.y), mk2(X3.x, X3.y), g2v);
  g2v = fma2(mk2(d3.z, d3.w), mk2(X3.z, X3.w), g2v);
  {
    const v2f* rowA = (const v2f*)&ldsA[wv][0];
    g2v = fma2(rowA[0], mk2(AC0.x, AC0.y), g2v);
    g2v = fma2(rowA[1], mk2(AC0.z, AC0.w), g2v);
    g2v = fma2(rowA[2], mk2(AC1.x, AC1.y), g2v);
    g2v = fma2(rowA[3], mk2(AC1.z, AC1.w), g2v);
    g2v = fma2(rowA[4], mk2(AC2.x, AC2.y), g2v);
    g2v = fma2(rowA[5], mk2(AC2.z, AC2.w), g2v);
    g2v = fma2(rowA[6], mk2(AC3.x, AC3.y), g2v);
    g2v = fma2(rowA[7], mk2(AC3.z, AC3.w), g2v);
  }
  float h2 = ftanh_pre((g2v.x + g2v.y) * TWO_LOG2E);

  float4 N0 = wp[22 * 64], N1 = wp[23 * 64], N2 = wp[24 * 64], N3 = wp[25 * 64];
  ldsS[wv][j] = h2;
  v2f ok2 = mk2(0.f, 0.f);
  {
    const v2f* rowS = (const v2f*)&ldsS[wv][g * 16];
    ok2 = fma2(rowS[0], mk2(N0.x, N0.y), ok2);
    ok2 = fma2(rowS[1], mk2(N0.z, N0.w), ok2);
    ok2 = fma2(rowS[2], mk2(N1.x, N1.y), ok2);
    ok2 = fma2(rowS[3], mk2(N1.z, N1.w), ok2);
    ok2 = fma2(rowS[4], mk2(N2.x, N2.y), ok2);
    ok2 = fma2(rowS[5], mk2(N2.z, N2.w), ok2);
    ok2 = fma2(rowS[6], mk2(N3.x, N3.y), ok2);
    ok2 = fma2(rowS[7], mk2(N3.z, N3.w), ok2);
  }
  float ok = ok2.x + ok2.y;
  ok += __shfl_xor(ok, 16, 64);
  ok += __shfl_xor(ok, 32, 64);

  // epilogue: k write + fused RK combine + optional output scatter
  if (j < 16) {
    float dt = dts[u];
    float kown = ok + MISC.w;
    int base = n * 16 + j;
    kout[base] = kown;
    float v = xb[base] + dt * cown * kown;
    if (kp0) v = fmaf(dt * c0, kp0[base], v);
    if (kp1) v = fmaf(dt * c1, kp1[base], v);
    if (kp2) v = fmaf(dt * c2, kp2[base], v);
    if (kp3) v = fmaf(dt * c3, kp3[base], v);
    xnext[base] = v;
    if (m >= 0) {
      #pragma unroll
      for (int rr = 0; rr < 10; rr++)
        if (mask_idx[rr] == m) dout[rr * (NN * 16) + base] = v;
    }
  }
}

// ---------------- host ----------------

extern "C" void kernel_launch(void* const* d_in, const int* in_sizes, int n_in,
                              void* d_out, int out_size, void* d_ws, size_t ws_size,
                              hipStream_t stream) {
  const float* x_hist = (const float*)d_in[0];
  const float* x_mask = (const float*)d_in[1];
  const int* edge_index = (const int*)d_in[2];
  const float* edge_attr = (const float*)d_in[3];
  const float* t = (const float*)d_in[4];
  const int* mask_idx = (const int*)d_in[5];
  const float* W1m = (const float*)d_in[6];
  const float* b1m = (const float*)d_in[7];
  const float* W2m = (const float*)d_in[8];
  const float* b2m = (const float*)d_in[9];
  const float* W1n = (const float*)d_in[10];
  const float* b1n = (const float*)d_in[11];
  const float* W2n = (const float*)d_in[12];
  const float* b2n = (const float*)d_in[13];
  float* out = (float*)d_out;

  size_t off = 0;
  char* wsb = (char*)d_ws;
  auto alloc = [&](size_t bytes) -> void* {
    void* p = (void*)(wsb + off);
    off += (bytes + 255) & ~(size_t)255;
    return p;
  };
  int* row_ptr = (int*)alloc((NN + 1) * sizeof(int));
  int* counts = (int*)alloc(NN * sizeof(int));
  int* src_sorted = (int*)alloc(EE * sizeof(int));
  float* ea_sorted = (float*)alloc((size_t)EE * 4 * sizeof(float));
  float* aug_pre = (float*)alloc((size_t)NN * 64 * sizeof(float));
  float* wpack = (float*)alloc((size_t)26 * 64 * 4 * sizeof(float));
  float* xA = (float*)alloc((size_t)NN * FF * sizeof(float));
  float* xB = (float*)alloc((size_t)NN * FF * sizeof(float));
  float* xiA = (float*)alloc((size_t)NN * FF * sizeof(float));
  float* xiB = (float*)alloc((size_t)NN * FF * sizeof(float));
  float* kb[6];
  for (int i = 0; i < 6; i++) kb[i] = (float*)alloc((size_t)NN * FF * sizeof(float));
  float* dts = (float*)alloc(40 * sizeof(float));
  float* tis = (float*)alloc(240 * sizeof(float));

  // CSR build + precompute
  hipMemsetAsync(counts, 0, NN * sizeof(int), stream);
  count_kernel<<<(EE + 255) / 256, 256, 0, stream>>>(edge_index, counts);
  scan_kernel<<<1, 1024, 0, stream>>>(counts, row_ptr);
  hipMemsetAsync(counts, 0, NN * sizeof(int), stream);
  fill_kernel<<<(EE + 255) / 256, 256, 0, stream>>>(edge_index, edge_attr, row_ptr, counts,
                                                    src_sorted, ea_sorted);
  prepack_kernel<<<1, 64, 0, stream>>>(W1m, b1m, W2m, b2m, W1n, W2n, b2n, wpack);
  augpre_kernel<<<256, 256, 0, stream>>>(x_hist, x_mask, W1n, b1n, aug_pre);
  times_kernel<<<1, 64, 0, stream>>>(t, dts, tis);
  hipMemcpyAsync(xA, x_hist + (size_t)9 * NN * FF, (size_t)NN * FF * sizeof(float),
                 hipMemcpyDeviceToDevice, stream);

  const int VG = NN / 4;  // 12500 blocks, 4 waves, 1 node/wave
  float* x = xA;
  float* xn = xB;

  auto vf = [&](const float* xin, float* ko, float* xnext,
                const float* p0, const float* p1, const float* p2, const float* p3,
                float c0, float c1, float c2, float c3, float cown,
                int u, int stage, float* doutp, int m) {
    vf_kernel<<<VG, 256, 0, stream>>>(xin, ko, x, xnext, p0, p1, p2, p3,
                                      c0, c1, c2, c3, cown,
                                      row_ptr, src_sorted, ea_sorted, aug_pre,
                                      dts, tis, u, u * 6 + stage, wpack,
                                      doutp, mask_idx, m);
  };

  for (int u = 0; u < 40; ++u) {
    vf(x, kb[0], xiA, nullptr, nullptr, nullptr, nullptr,
       0.f, 0.f, 0.f, 0.f, 0.2f, u, 0, nullptr, -1);
    vf(xiA, kb[1], xiB, kb[0], nullptr, nullptr, nullptr,
       0.075f, 0.f, 0.f, 0.f, 0.225f, u, 1, nullptr, -1);
    vf(xiB, kb[2], xiA, kb[0], kb[1], nullptr, nullptr,
       (float)(44.0 / 45.0), (float)(-56.0 / 15.0), 0.f, 0.f, (float)(32.0 / 9.0),
       u, 2, nullptr, -1);
    vf(xiA, kb[3], xiB, kb[0], kb[1], kb[2], nullptr,
       (float)(19372.0 / 6561.0), (float)(-25360.0 / 2187.0), (float)(64448.0 / 6561.0),
       0.f, (float)(-212.0 / 729.0), u, 3, nullptr, -1);
    vf(xiB, kb[4], xiA, kb[0], kb[1], kb[2], kb[3],
       (float)(9017.0 / 3168.0), (float)(-355.0 / 33.0), (float)(46732.0 / 5247.0),
       (float)(49.0 / 176.0), (float)(-5103.0 / 18656.0), u, 4, nullptr, -1);
    int m = ((u & 3) == 3) ? (u >> 2) : -1;
    vf(xiA, kb[5], xn, kb[0], kb[2], kb[3], kb[4],
       (float)(35.0 / 384.0), (float)(500.0 / 1113.0), (float)(125.0 / 192.0),
       (float)(-2187.0 / 6784.0), (float)(11.0 / 84.0), u, 5, out, m);
    float* tmp = x; x = xn; xn = tmp;
  }
}

// Round 7
// 14930.992 us; speedup vs baseline: 5.4135x; 1.2170x over previous
//
#include <hip/hip_runtime.h>

#define NN 50000
#define FF 16
#define TH 10
#define EE 800000

#define TWO_LOG2E 2.8853900817779268f  // 2*log2(e)

typedef __attribute__((ext_vector_type(2))) float v2f;

__device__ __forceinline__ float fexp2(float x) { return __builtin_amdgcn_exp2f(x); }
__device__ __forceinline__ float frcp(float x) { return __builtin_amdgcn_rcpf(x); }
__device__ __forceinline__ float ftanh_pre(float xs) {  // operand pre-scaled by 2log2e
  float e = fexp2(xs);
  return 1.0f - 2.0f * frcp(e + 1.0f);
}
__device__ __forceinline__ v2f mk2(float a, float b) { v2f r; r.x = a; r.y = b; return r; }
__device__ __forceinline__ v2f fma2(v2f a, v2f b, v2f c) { return __builtin_elementwise_fma(a, b, c); }

// ---------------- preprocessing ----------------

__global__ void count_kernel(const int* __restrict__ ei, int* __restrict__ counts) {
  int e = blockIdx.x * 256 + threadIdx.x;
  if (e < EE) atomicAdd(&counts[ei[EE + e]], 1);
}

__global__ void scan_kernel(const int* __restrict__ counts, int* __restrict__ row_ptr) {
  __shared__ int lds[1024];
  const int CH = (NN + 1023) / 1024;  // 49
  int t = threadIdx.x;
  int beg = t * CH, end = beg + CH;
  if (beg > NN) beg = NN;
  if (end > NN) end = NN;
  int s = 0;
  for (int i = beg; i < end; i++) s += counts[i];
  lds[t] = s;
  __syncthreads();
  for (int off = 1; off < 1024; off <<= 1) {
    int v = (t >= off) ? lds[t - off] : 0;
    __syncthreads();
    lds[t] += v;
    __syncthreads();
  }
  int run = lds[t] - s;  // exclusive prefix
  for (int i = beg; i < end; i++) { row_ptr[i] = run; run += counts[i]; }
  if (t == 1023) row_ptr[NN] = lds[1023];
}

__global__ void fill_kernel(const int* __restrict__ ei, const float* __restrict__ ea,
                            const int* __restrict__ row_ptr, int* __restrict__ cursor,
                            int* __restrict__ src_sorted, float* __restrict__ ea_sorted) {
  int e = blockIdx.x * 256 + threadIdx.x;
  if (e >= EE) return;
  int d = ei[EE + e];
  int pos = row_ptr[d] + atomicAdd(&cursor[d], 1);
  src_sorted[pos] = ei[e];
  ((float4*)ea_sorted)[pos] = ((const float4*)ea)[e];
}

__global__ void times_kernel(const float* __restrict__ t, float* __restrict__ dts,
                             float* __restrict__ tis) {
  int u = threadIdx.x;
  if (u >= 40) return;
  int iv = u >> 2, fr = u & 3;
  float dti = (t[iv + 1] - t[iv]) * 0.25f;
  dts[u] = dti;
  float t0 = t[iv] + (float)fr * dti;
  const float C[6] = {0.0f, 0.2f, 0.3f, 0.8f, (float)(8.0 / 9.0), 1.0f};
  for (int s = 0; s < 6; s++) tis[u * 6 + s] = t0 + C[s] * dti;
}

// Prepacked per-lane weight blob (26 chunks of 64 x float4, coalesced):
//  c0..3  Uc  (W1m rows 0..15,  prescaled by 2log2e)
//  c4..7  Vc  (W1m rows 16..31, prescaled)
//  c8     Ec  (W1m rows 32..35, prescaled)
//  c9     misc: {b1m[j]*2log2e, W1n[208][j] (tw), b2m[j&15], b2n[j&15]}
//  c10..13 Xc (W1n rows 0..15)
//  c14..17 Ac (W1n rows 16..31)
//  c18..21 W2mT (W2m[(g*16+q)][kk])
//  c22..25 W2nT
__global__ void prepack_kernel(const float* __restrict__ W1m, const float* __restrict__ b1m,
                               const float* __restrict__ W2m, const float* __restrict__ b2m,
                               const float* __restrict__ W1n, const float* __restrict__ W2n,
                               const float* __restrict__ b2n, float* __restrict__ wp) {
  int j = threadIdx.x;
  if (j >= 64) return;
  int g = j >> 4, kk = j & 15;
  auto put = [&](int c, int r, float v) { wp[(size_t)(c * 64 + j) * 4 + r] = v; };
  for (int c = 0; c < 4; c++)
    for (int r = 0; r < 4; r++) {
      put(c, r, W1m[(4 * c + r) * 64 + j] * TWO_LOG2E);
      put(4 + c, r, W1m[(16 + 4 * c + r) * 64 + j] * TWO_LOG2E);
      put(10 + c, r, W1n[(4 * c + r) * 64 + j]);
      put(14 + c, r, W1n[(16 + 4 * c + r) * 64 + j]);
      put(18 + c, r, W2m[(g * 16 + 4 * c + r) * 16 + kk]);
      put(22 + c, r, W2n[(g * 16 + 4 * c + r) * 16 + kk]);
    }
  for (int r = 0; r < 4; r++) put(8, r, W1m[(32 + r) * 64 + j] * TWO_LOG2E);
  put(9, 0, b1m[j] * TWO_LOG2E);
  put(9, 1, W1n[208 * 64 + j]);
  put(9, 2, b2m[kk]);
  put(9, 3, b2n[kk]);
}

// aug_pre[n][j] = b1n[j] + sum_i aug[n][i] * W1n[32+i][j]   (176-dim aug)
__global__ __launch_bounds__(256) void augpre_kernel(
    const float* __restrict__ xh, const float* __restrict__ xm,
    const float* __restrict__ W1n, const float* __restrict__ b1n,
    float* __restrict__ aug_pre) {
  __shared__ float Wl[176 * 64];
  __shared__ float augl[4][176];
  for (int i = threadIdx.x; i < 176 * 64; i += 256) Wl[i] = W1n[32 * 64 + i];
  __syncthreads();
  int wv = threadIdx.x >> 6, j = threadIdx.x & 63;
  float bj = b1n[j];
  for (int base = blockIdx.x * 4; base < NN; base += gridDim.x * 4) {
    int n = base + wv;  // NN % 4 == 0
    if (j < 16) {
      int f = j;
      float xv[TH], mv[TH], summ = 0.f;
      #pragma unroll
      for (int tt = 0; tt < TH; tt++) {
        xv[tt] = xh[(tt * NN + n) * FF + f];
        mv[tt] = xm[tt * NN + n];
        summ += mv[tt];
      }
      float cnt = fmaxf(summ, 1.0f);
      float mean = 0.f;
      #pragma unroll
      for (int tt = 0; tt < TH; tt++) mean += xv[tt] * mv[tt];
      mean *= frcp(cnt);
      float var = 0.f;
      #pragma unroll
      for (int tt = 0; tt < TH; tt++) { float d = xv[tt] - mean; var += d * d * mv[tt]; }
      var *= frcp(cnt);
      #pragma unroll
      for (int tt = 0; tt < TH - 1; tt++)
        augl[wv][tt * 16 + f] = (xv[tt + 1] - xv[tt]) * (mv[tt + 1] * mv[tt]);
      augl[wv][144 + f] = mean;
      augl[wv][160 + f] = var;
    }
    __syncthreads();
    float acc = bj;
    #pragma unroll 8
    for (int i = 0; i < 176; i++) acc += augl[wv][i] * Wl[i * 64 + j];
    aug_pre[n * 64 + j] = acc;
    __syncthreads();
  }
}

// P[n][j] = x[n]·U_pre  (bootstrap for the initial state)
__global__ __launch_bounds__(256, 4) void pqinit_kernel(
    const float* __restrict__ x0, const float* __restrict__ wpack,
    float* __restrict__ Pout) {
  int wv = threadIdx.x >> 6, j = threadIdx.x & 63;
  int n = blockIdx.x * 4 + wv;
  int n_s = __builtin_amdgcn_readfirstlane(n);
  const float4* wp = (const float4*)wpack + j;
  float4 U0 = wp[0 * 64], U1 = wp[1 * 64], U2 = wp[2 * 64], U3 = wp[3 * 64];
  const float4* xr = (const float4*)(x0 + (size_t)n_s * 16);
  float4 d0 = xr[0], d1 = xr[1], d2 = xr[2], d3 = xr[3];
  v2f pn = mk2(0.f, 0.f);
  pn = fma2(mk2(d0.x, d0.y), mk2(U0.x, U0.y), pn);
  pn = fma2(mk2(d0.z, d0.w), mk2(U0.z, U0.w), pn);
  pn = fma2(mk2(d1.x, d1.y), mk2(U1.x, U1.y), pn);
  pn = fma2(mk2(d1.z, d1.w), mk2(U1.z, U1.w), pn);
  pn = fma2(mk2(d2.x, d2.y), mk2(U2.x, U2.y), pn);
  pn = fma2(mk2(d2.z, d2.w), mk2(U2.z, U2.w), pn);
  pn = fma2(mk2(d3.x, d3.y), mk2(U3.x, U3.y), pn);
  pn = fma2(mk2(d3.z, d3.w), mk2(U3.z, U3.w), pn);
  Pout[(size_t)n * 64 + j] = pn.x + pn.y;
}

// ---------------- fused vector field + RK combine + P-for-next-stage ----------------
// 1 node/wave. Per edge: ONE coalesced 256B gather of P[src] (lane j gets its
// own float) + uniform ea float4 + 9 VALU. Epilogue computes P(xnext).

__global__ __launch_bounds__(256, 4) void vf_kernel(
    const float* __restrict__ xi, float* __restrict__ kout,
    const float* __restrict__ xb, float* __restrict__ xnext,
    const float* __restrict__ kp0, const float* __restrict__ kp1,
    const float* __restrict__ kp2, const float* __restrict__ kp3,
    float c0, float c1, float c2, float c3, float cown,
    const int* __restrict__ row_ptr, const int* __restrict__ srcs,
    const float* __restrict__ eas, const float* __restrict__ aug_pre,
    const float* __restrict__ dts, const float* __restrict__ tis,
    int u, int tidx, const float* __restrict__ wpack,
    const float* __restrict__ Pin, float* __restrict__ Pout,
    float* __restrict__ dout, const int* __restrict__ mask_idx, int m) {
  __shared__ float ldsS[4][64];
  __shared__ float ldsA[4][16];
  int wv = threadIdx.x >> 6, j = threadIdx.x & 63;
  int g = j >> 4;
  int n = blockIdx.x * 4 + wv;
  int n_s = __builtin_amdgcn_readfirstlane(n);

  const float4* wp = (const float4*)wpack + j;  // chunk c at wp[c*64]
  float4 E4 = wp[8 * 64];
  float4 MISC = wp[9 * 64];  // {b1pre, tw, b2mk, b2nk}

  // Qj = b1pre + x[dst]·V_pre
  const float4* xr = (const float4*)(xi + (size_t)n_s * 16);
  float4 d0 = xr[0], d1 = xr[1], d2 = xr[2], d3 = xr[3];
  float Qj;
  {
    float4 V0 = wp[4 * 64], V1 = wp[5 * 64], V2 = wp[6 * 64], V3 = wp[7 * 64];
    v2f q2 = mk2(MISC.x, 0.f);
    q2 = fma2(mk2(d0.x, d0.y), mk2(V0.x, V0.y), q2);
    q2 = fma2(mk2(d0.z, d0.w), mk2(V0.z, V0.w), q2);
    q2 = fma2(mk2(d1.x, d1.y), mk2(V1.x, V1.y), q2);
    q2 = fma2(mk2(d1.z, d1.w), mk2(V1.z, V1.w), q2);
    q2 = fma2(mk2(d2.x, d2.y), mk2(V2.x, V2.y), q2);
    q2 = fma2(mk2(d2.z, d2.w), mk2(V2.z, V2.w), q2);
    q2 = fma2(mk2(d3.x, d3.y), mk2(V3.x, V3.y), q2);
    q2 = fma2(mk2(d3.z, d3.w), mk2(V3.z, V3.w), q2);
    Qj = q2.x + q2.y;
  }

  int e0s = __builtin_amdgcn_readfirstlane(row_ptr[n_s]);
  int e1s = __builtin_amdgcn_readfirstlane(row_ptr[n_s + 1]);
  float sj = 0.f;  // accumulates -2*sum(r); deg added at end

  for (int e = e0s; e < e1s; e += 64) {
    int cnt = e1s - e;
    if (cnt > 64) cnt = 64;
    int myidx = (j < cnt) ? srcs[e + j] : 0;  // 1 coalesced load per <=64 edges
    int p = 0;
    for (; p + 7 < cnt; p += 8) {  // 8 gathers + 8 ea loads in flight
      float Ps[8];
      float4 eav[8];
      #pragma unroll
      for (int i = 0; i < 8; i++) {
        int sp = __builtin_amdgcn_readlane(myidx, p + i);
        Ps[i] = Pin[(size_t)sp * 64 + j];
        eav[i] = ((const float4*)eas)[e + p + i];
      }
      #pragma unroll
      for (int i = 0; i < 8; i++) {
        float h = Ps[i] + Qj;
        h = fmaf(eav[i].x, E4.x, h);
        h = fmaf(eav[i].y, E4.y, h);
        h = fmaf(eav[i].z, E4.z, h);
        h = fmaf(eav[i].w, E4.w, h);
        float r = frcp(fexp2(h) + 1.0f);
        sj = fmaf(-2.0f, r, sj);
      }
    }
    for (; p < cnt; p++) {
      int sp = __builtin_amdgcn_readlane(myidx, p);
      float Ps = Pin[(size_t)sp * 64 + j];
      float4 eav = ((const float4*)eas)[e + p];
      float h = Ps + Qj;
      h = fmaf(eav.x, E4.x, h);
      h = fmaf(eav.y, E4.y, h);
      h = fmaf(eav.z, E4.z, h);
      h = fmaf(eav.w, E4.w, h);
      float r = frcp(fexp2(h) + 1.0f);
      sj = fmaf(-2.0f, r, sj);
    }
  }
  float deg = (float)(e1s - e0s);
  sj += deg;  // tanh = 1 - 2r; the +1 per edge folded here

  // agg[k] = sum_j tanh_sum * W2m[j][k] + deg*b2m[k]   (4-group LDS transpose)
  float4 M0 = wp[18 * 64], M1 = wp[19 * 64], M2 = wp[20 * 64], M3 = wp[21 * 64];
  ldsS[wv][j] = sj;
  v2f pk2 = mk2(0.f, 0.f);
  {
    const v2f* rowS = (const v2f*)&ldsS[wv][g * 16];
    pk2 = fma2(rowS[0], mk2(M0.x, M0.y), pk2);
    pk2 = fma2(rowS[1], mk2(M0.z, M0.w), pk2);
    pk2 = fma2(rowS[2], mk2(M1.x, M1.y), pk2);
    pk2 = fma2(rowS[3], mk2(M1.z, M1.w), pk2);
    pk2 = fma2(rowS[4], mk2(M2.x, M2.y), pk2);
    pk2 = fma2(rowS[5], mk2(M2.z, M2.w), pk2);
    pk2 = fma2(rowS[6], mk2(M3.x, M3.y), pk2);
    pk2 = fma2(rowS[7], mk2(M3.z, M3.w), pk2);
  }
  float pk = pk2.x + pk2.y;
  pk += __shfl_xor(pk, 16, 64);
  pk += __shfl_xor(pk, 32, 64);
  ldsA[wv][j & 15] = pk + deg * MISC.z;

  // node MLP
  float4 X0 = wp[10 * 64], X1 = wp[11 * 64], X2 = wp[12 * 64], X3 = wp[13 * 64];
  float4 AC0 = wp[14 * 64], AC1 = wp[15 * 64], AC2 = wp[16 * 64], AC3 = wp[17 * 64];
  float ti = tis[tidx];
  v2f g2v = mk2(aug_pre[(size_t)n * 64 + j] + ti * MISC.y, 0.f);
  g2v = fma2(mk2(d0.x, d0.y), mk2(X0.x, X0.y), g2v);
  g2v = fma2(mk2(d0.z, d0.w), mk2(X0.z, X0.w), g2v);
  g2v = fma2(mk2(d1.x, d1.y), mk2(X1.x, X1.y), g2v);
  g2v = fma2(mk2(d1.z, d1.w), mk2(X1.z, X1.w), g2v);
  g2v = fma2(mk2(d2.x, d2.y), mk2(X2.x, X2.y), g2v);
  g2v = fma2(mk2(d2.z, d2.w), mk2(X2.z, X2.w), g2v);
  g2v = fma2(mk2(d3.x, d3.y), mk2(X3.x, X3.y), g2v);
  g2v = fma2(mk2(d3.z, d3.w), mk2(X3.z, X3.w), g2v);
  {
    const v2f* rowA = (const v2f*)&ldsA[wv][0];
    g2v = fma2(rowA[0], mk2(AC0.x, AC0.y), g2v);
    g2v = fma2(rowA[1], mk2(AC0.z, AC0.w), g2v);
    g2v = fma2(rowA[2], mk2(AC1.x, AC1.y), g2v);
    g2v = fma2(rowA[3], mk2(AC1.z, AC1.w), g2v);
    g2v = fma2(rowA[4], mk2(AC2.x, AC2.y), g2v);
    g2v = fma2(rowA[5], mk2(AC2.z, AC2.w), g2v);
    g2v = fma2(rowA[6], mk2(AC3.x, AC3.y), g2v);
    g2v = fma2(rowA[7], mk2(AC3.z, AC3.w), g2v);
  }
  float h2 = ftanh_pre((g2v.x + g2v.y) * TWO_LOG2E);

  float4 N0 = wp[22 * 64], N1 = wp[23 * 64], N2 = wp[24 * 64], N3 = wp[25 * 64];
  ldsS[wv][j] = h2;
  v2f ok2 = mk2(0.f, 0.f);
  {
    const v2f* rowS = (const v2f*)&ldsS[wv][g * 16];
    ok2 = fma2(rowS[0], mk2(N0.x, N0.y), ok2);
    ok2 = fma2(rowS[1], mk2(N0.z, N0.w), ok2);
    ok2 = fma2(rowS[2], mk2(N1.x, N1.y), ok2);
    ok2 = fma2(rowS[3], mk2(N1.z, N1.w), ok2);
    ok2 = fma2(rowS[4], mk2(N2.x, N2.y), ok2);
    ok2 = fma2(rowS[5], mk2(N2.z, N2.w), ok2);
    ok2 = fma2(rowS[6], mk2(N3.x, N3.y), ok2);
    ok2 = fma2(rowS[7], mk2(N3.z, N3.w), ok2);
  }
  float ok = ok2.x + ok2.y;
  ok += __shfl_xor(ok, 16, 64);
  ok += __shfl_xor(ok, 32, 64);

  // epilogue: k write + fused RK combine + xnext-row broadcast for P(next)
  if (j < 16) {
    float dt = dts[u];
    float kown = ok + MISC.w;
    int base = n * 16 + j;
    kout[base] = kown;
    float v = xb[base] + dt * cown * kown;
    if (kp0) v = fmaf(dt * c0, kp0[base], v);
    if (kp1) v = fmaf(dt * c1, kp1[base], v);
    if (kp2) v = fmaf(dt * c2, kp2[base], v);
    if (kp3) v = fmaf(dt * c3, kp3[base], v);
    xnext[base] = v;
    ldsA[wv][j] = v;  // broadcast xnext row to whole wave
    if (m >= 0) {
      #pragma unroll
      for (int rr = 0; rr < 10; rr++)
        if (mask_idx[rr] == m) dout[rr * (NN * 16) + base] = v;
    }
  }

  // P(xnext)[n][j] = xnext·U_pre  -> next stage's edge phase reads this
  {
    float4 U0 = wp[0 * 64], U1 = wp[1 * 64], U2 = wp[2 * 64], U3 = wp[3 * 64];
    const v2f* rowV = (const v2f*)&ldsA[wv][0];
    v2f pn = mk2(0.f, 0.f);
    pn = fma2(rowV[0], mk2(U0.x, U0.y), pn);
    pn = fma2(rowV[1], mk2(U0.z, U0.w), pn);
    pn = fma2(rowV[2], mk2(U1.x, U1.y), pn);
    pn = fma2(rowV[3], mk2(U1.z, U1.w), pn);
    pn = fma2(rowV[4], mk2(U2.x, U2.y), pn);
    pn = fma2(rowV[5], mk2(U2.z, U2.w), pn);
    pn = fma2(rowV[6], mk2(U3.x, U3.y), pn);
    pn = fma2(rowV[7], mk2(U3.z, U3.w), pn);
    Pout[(size_t)n * 64 + j] = pn.x + pn.y;
  }
}

// ---------------- host ----------------

extern "C" void kernel_launch(void* const* d_in, const int* in_sizes, int n_in,
                              void* d_out, int out_size, void* d_ws, size_t ws_size,
                              hipStream_t stream) {
  const float* x_hist = (const float*)d_in[0];
  const float* x_mask = (const float*)d_in[1];
  const int* edge_index = (const int*)d_in[2];
  const float* edge_attr = (const float*)d_in[3];
  const float* t = (const float*)d_in[4];
  const int* mask_idx = (const int*)d_in[5];
  const float* W1m = (const float*)d_in[6];
  const float* b1m = (const float*)d_in[7];
  const float* W2m = (const float*)d_in[8];
  const float* b2m = (const float*)d_in[9];
  const float* W1n = (const float*)d_in[10];
  const float* b1n = (const float*)d_in[11];
  const float* W2n = (const float*)d_in[12];
  const float* b2n = (const float*)d_in[13];
  float* out = (float*)d_out;

  size_t off = 0;
  char* wsb = (char*)d_ws;
  auto alloc = [&](size_t bytes) -> void* {
    void* p = (void*)(wsb + off);
    off += (bytes + 255) & ~(size_t)255;
    return p;
  };
  int* row_ptr = (int*)alloc((NN + 1) * sizeof(int));
  int* counts = (int*)alloc(NN * sizeof(int));
  int* src_sorted = (int*)alloc(EE * sizeof(int));
  float* ea_sorted = (float*)alloc((size_t)EE * 4 * sizeof(float));
  float* aug_pre = (float*)alloc((size_t)NN * 64 * sizeof(float));
  float* wpack = (float*)alloc((size_t)26 * 64 * 4 * sizeof(float));
  float* Pa = (float*)alloc((size_t)NN * 64 * sizeof(float));
  float* Pb = (float*)alloc((size_t)NN * 64 * sizeof(float));
  float* xA = (float*)alloc((size_t)NN * FF * sizeof(float));
  float* xB = (float*)alloc((size_t)NN * FF * sizeof(float));
  float* xiA = (float*)alloc((size_t)NN * FF * sizeof(float));
  float* xiB = (float*)alloc((size_t)NN * FF * sizeof(float));
  float* kb[6];
  for (int i = 0; i < 6; i++) kb[i] = (float*)alloc((size_t)NN * FF * sizeof(float));
  float* dts = (float*)alloc(40 * sizeof(float));
  float* tis = (float*)alloc(240 * sizeof(float));

  // CSR build + precompute
  hipMemsetAsync(counts, 0, NN * sizeof(int), stream);
  count_kernel<<<(EE + 255) / 256, 256, 0, stream>>>(edge_index, counts);
  scan_kernel<<<1, 1024, 0, stream>>>(counts, row_ptr);
  hipMemsetAsync(counts, 0, NN * sizeof(int), stream);
  fill_kernel<<<(EE + 255) / 256, 256, 0, stream>>>(edge_index, edge_attr, row_ptr, counts,
                                                    src_sorted, ea_sorted);
  prepack_kernel<<<1, 64, 0, stream>>>(W1m, b1m, W2m, b2m, W1n, W2n, b2n, wpack);
  augpre_kernel<<<256, 256, 0, stream>>>(x_hist, x_mask, W1n, b1n, aug_pre);
  times_kernel<<<1, 64, 0, stream>>>(t, dts, tis);
  hipMemcpyAsync(xA, x_hist + (size_t)9 * NN * FF, (size_t)NN * FF * sizeof(float),
                 hipMemcpyDeviceToDevice, stream);
  pqinit_kernel<<<NN / 4, 256, 0, stream>>>(xA, wpack, Pa);

  const int VG = NN / 4;  // 12500 blocks, 4 waves, 1 node/wave
  float* x = xA;
  float* xn = xB;
  int sidx = 0;  // global stage index; P parity = sidx & 1

  auto vf = [&](const float* xin, float* ko, float* xnext,
                const float* p0, const float* p1, const float* p2, const float* p3,
                float c0, float c1, float c2, float c3, float cown,
                int u, int stage, float* doutp, int m) {
    float* Pin = (sidx & 1) ? Pb : Pa;
    float* Pout = (sidx & 1) ? Pa : Pb;
    vf_kernel<<<VG, 256, 0, stream>>>(xin, ko, x, xnext, p0, p1, p2, p3,
                                      c0, c1, c2, c3, cown,
                                      row_ptr, src_sorted, ea_sorted, aug_pre,
                                      dts, tis, u, u * 6 + stage, wpack,
                                      Pin, Pout, doutp, mask_idx, m);
    sidx++;
  };

  for (int u = 0; u < 40; ++u) {
    vf(x, kb[0], xiA, nullptr, nullptr, nullptr, nullptr,
       0.f, 0.f, 0.f, 0.f, 0.2f, u, 0, nullptr, -1);
    vf(xiA, kb[1], xiB, kb[0], nullptr, nullptr, nullptr,
       0.075f, 0.f, 0.f, 0.f, 0.225f, u, 1, nullptr, -1);
    vf(xiB, kb[2], xiA, kb[0], kb[1], nullptr, nullptr,
       (float)(44.0 / 45.0), (float)(-56.0 / 15.0), 0.f, 0.f, (float)(32.0 / 9.0),
       u, 2, nullptr, -1);
    vf(xiA, kb[3], xiB, kb[0], kb[1], kb[2], nullptr,
       (float)(19372.0 / 6561.0), (float)(-25360.0 / 2187.0), (float)(64448.0 / 6561.0),
       0.f, (float)(-212.0 / 729.0), u, 3, nullptr, -1);
    vf(xiB, kb[4], xiA, kb[0], kb[1], kb[2], kb[3],
       (float)(9017.0 / 3168.0), (float)(-355.0 / 33.0), (float)(46732.0 / 5247.0),
       (float)(49.0 / 176.0), (float)(-5103.0 / 18656.0), u, 4, nullptr, -1);
    int m = ((u & 3) == 3) ? (u >> 2) : -1;
    vf(xiA, kb[5], xn, kb[0], kb[2], kb[3], kb[4],
       (float)(35.0 / 384.0), (float)(500.0 / 1113.0), (float)(125.0 / 192.0),
       (float)(-2187.0 / 6784.0), (float)(11.0 / 84.0), u, 5, out, m);
    float* tmp = x; x = xn; xn = tmp;
  }
}